// Round 1
// baseline (277.112 us; speedup 1.0000x reference)
//
#include <hip/hip_runtime.h>

// types
typedef __attribute__((ext_vector_type(8))) short bf16x8;
typedef __attribute__((ext_vector_type(4))) float f32x4;

#define DEVI static __device__ __forceinline__

DEVI unsigned short f2b(float f) {
  union { float f; unsigned u; } v; v.f = f;
  unsigned r = v.u + 0x7fffu + ((v.u >> 16) & 1u);
  return (unsigned short)(r >> 16);
}

typedef const __attribute__((address_space(1))) void* gas1_t;
typedef __attribute__((address_space(3))) void* las3_t;
#define GL16(g, l) __builtin_amdgcn_global_load_lds((gas1_t)(g), (las3_t)(l), 16, 0, 0)

// ---- workspace layout (bytes) ----
// weights block
#define OFF_WQKV  0ull          // 768*512*2 = 786432
#define OFF_WR    786432ull     // 512*256*2 = 262144
#define OFF_BQKV  1048576ull    // 768*4
#define OFF_SCALE 1051648ull    // 512*4
#define OFF_OFF2  1053696ull    // 512*4
// big buffers
#define OFF_XT    2097152ull            // xt bf16 [16][4096][512] = 64 MiB
#define OFF_YT    2097152ull            // yt bf16 [16][4096][256] = 32 MiB (reuses xt region after G1)
#define OFF_Y     35651584ull           // y  bf16 [16][256][4096] = 32 MiB (second half of xt region)
#define OFF_Q     69206016ull           // qkv bf16: q,k,v each 16777216 u16 elements, contiguous

// ---------------- P0: weight prep ----------------
__global__ __launch_bounds__(256) void k_prep(
    const float* __restrict__ Wq, const float* __restrict__ bq,
    const float* __restrict__ Wk, const float* __restrict__ bk,
    const float* __restrict__ Wv, const float* __restrict__ bv,
    const float* __restrict__ Wr, const float* __restrict__ br,
    const float* __restrict__ gamma, const float* __restrict__ beta,
    const float* __restrict__ rm, const float* __restrict__ rv,
    unsigned short* __restrict__ wqkv, unsigned short* __restrict__ wrb,
    float* __restrict__ bqkv, float* __restrict__ scale, float* __restrict__ off2)
{
  int i = blockIdx.x * 256 + threadIdx.x;
  if (i < 768 * 512) {
    int o = i >> 9, c = i & 511;
    float v = (o < 256) ? Wq[o * 512 + c] : (o < 512 ? Wk[(o - 256) * 512 + c] : Wv[(o - 512) * 512 + c]);
    wqkv[i] = f2b(v);
  }
  if (i < 512 * 256) wrb[i] = f2b(Wr[i]);
  if (i < 768) bqkv[i] = (i < 256) ? bq[i] : (i < 512 ? bk[i - 256] : bv[i - 512]);
  if (i < 512) {
    float inv = gamma[i] * rsqrtf(rv[i] + 1e-5f);
    scale[i] = inv;
    off2[i] = (br[i] - rm[i]) * inv + beta[i];
  }
}

// ---------------- P1: x [B][C][S] f32 -> xt [B][S][C] bf16 ----------------
__global__ __launch_bounds__(256) void k_xt(const float* __restrict__ x, unsigned short* __restrict__ xt)
{
  __shared__ unsigned short tile[64][72];
  const int b = blockIdx.z, c0 = blockIdx.y * 64, s0 = blockIdx.x * 64;
  const int t = threadIdx.x;
  const int r = t >> 2, cc = (t & 3) * 16;
  const float* src = x + ((size_t)b * 512 + c0 + r) * 4096 + s0 + cc;
  #pragma unroll
  for (int j = 0; j < 16; j += 4) {
    float4 v = *(const float4*)(src + j);
    tile[r][cc + j + 0] = f2b(v.x);
    tile[r][cc + j + 1] = f2b(v.y);
    tile[r][cc + j + 2] = f2b(v.z);
    tile[r][cc + j + 3] = f2b(v.w);
  }
  __syncthreads();
  unsigned short* dst = xt + ((size_t)b * 4096 + s0 + r) * 512 + c0 + cc;
  bf16x8 o0, o1;
  #pragma unroll
  for (int j = 0; j < 8; ++j) { o0[j] = tile[cc + j][r]; o1[j] = tile[cc + 8 + j][r]; }
  *(bf16x8*)(dst) = o0;
  *(bf16x8*)(dst + 8) = o1;
}

// ---------------- G1: QKV GEMM  D[o, s] = Wqkv[o,:] . xt[b][s][:] ----------------
__global__ __launch_bounds__(256) void k_qkv(
    const unsigned short* __restrict__ xt, const unsigned short* __restrict__ wqkv,
    const float* __restrict__ bqkv, unsigned short* __restrict__ qkv)
{
  __shared__ unsigned short lds[2][2][4096];  // [buf][A/B][128*32]
  const int b = blockIdx.z, o0 = blockIdx.y * 128, s0 = blockIdx.x * 128;
  const int t = threadIdx.x, w = t >> 6, l = t & 63;
  const int wm = w >> 1, wn = w & 1, lr = l & 15, koff = (l >> 4) * 8;

  const unsigned short* Ag = wqkv + (size_t)(o0 + (t >> 2)) * 512 + (t & 3) * 8;
  const unsigned short* Bg = xt + ((size_t)b * 4096 + s0 + (t >> 2)) * 512 + (t & 3) * 8;

  const f32x4 z = {0.f, 0.f, 0.f, 0.f};
  f32x4 acc[4][4];
  #pragma unroll
  for (int i = 0; i < 4; ++i)
    #pragma unroll
    for (int j = 0; j < 4; ++j) acc[i][j] = z;

  GL16(Ag, (char*)&lds[0][0][0] + t * 16);
  GL16(Ag + 64 * 512, (char*)&lds[0][0][0] + t * 16 + 4096);
  GL16(Bg, (char*)&lds[0][1][0] + t * 16);
  GL16(Bg + 64 * 512, (char*)&lds[0][1][0] + t * 16 + 4096);

  int cur = 0;
  for (int kt = 0; kt < 16; ++kt) {
    __syncthreads();
    if (kt + 1 < 16) {
      const unsigned short* a2 = Ag + (kt + 1) * 32;
      const unsigned short* b2 = Bg + (kt + 1) * 32;
      GL16(a2, (char*)&lds[cur ^ 1][0][0] + t * 16);
      GL16(a2 + 64 * 512, (char*)&lds[cur ^ 1][0][0] + t * 16 + 4096);
      GL16(b2, (char*)&lds[cur ^ 1][1][0] + t * 16);
      GL16(b2 + 64 * 512, (char*)&lds[cur ^ 1][1][0] + t * 16 + 4096);
    }
    const unsigned short* A = &lds[cur][0][0];
    const unsigned short* Bl = &lds[cur][1][0];
    bf16x8 af[4], bf[4];
    #pragma unroll
    for (int mi = 0; mi < 4; ++mi) af[mi] = *(const bf16x8*)(A + (wm * 64 + mi * 16 + lr) * 32 + koff);
    #pragma unroll
    for (int ni = 0; ni < 4; ++ni) bf[ni] = *(const bf16x8*)(Bl + (wn * 64 + ni * 16 + lr) * 32 + koff);
    #pragma unroll
    for (int mi = 0; mi < 4; ++mi)
      #pragma unroll
      for (int ni = 0; ni < 4; ++ni)
        acc[mi][ni] = __builtin_amdgcn_mfma_f32_16x16x32_bf16(af[mi], bf[ni], acc[mi][ni], 0, 0, 0);
    cur ^= 1;
  }

  // epilogue: D row = o (lane>>4)*4+reg, col = s (lane&15); store bf16 to q/k/v
  #pragma unroll
  for (int mi = 0; mi < 4; ++mi) {
    #pragma unroll
    for (int reg = 0; reg < 4; ++reg) {
      const int o = o0 + wm * 64 + mi * 16 + (l >> 4) * 4 + reg;
      const float bias = bqkv[o];
      const size_t base = (size_t)(o >> 8) * 16777216ull + ((size_t)b * 256 + (o & 255)) * 4096;
      #pragma unroll
      for (int ni = 0; ni < 4; ++ni) {
        const int s = s0 + wn * 64 + ni * 16 + lr;
        qkv[base + s] = f2b(acc[mi][ni][reg] + bias);
      }
    }
  }
}

// ---------------- G2: per-group attention (g = b*256+cr), 4 waves x 16-row strips ----------------
__global__ __launch_bounds__(256) void k_attn(const unsigned short* __restrict__ qkv,
                                              unsigned short* __restrict__ yout)
{
  __shared__ unsigned short Vt[64][80];     // V transposed: Vt[n][j]
  __shared__ unsigned short P[4][16][80];   // per-wave P strip [row][j]
  const int g = blockIdx.x;
  const unsigned short* qg = qkv + (size_t)g * 4096;
  const unsigned short* kg = qkv + 16777216ull + (size_t)g * 4096;
  const unsigned short* vg = qkv + 33554432ull + (size_t)g * 4096;
  const int t = threadIdx.x, w = t >> 6, l = t & 63;
  const int lr = l & 15, lk = (l >> 4) * 8;

  // stage V transposed into LDS
  {
    const int j = t >> 2, c0 = (t & 3) * 16;
    bf16x8 a = *(const bf16x8*)(vg + j * 64 + c0);
    bf16x8 bb = *(const bf16x8*)(vg + j * 64 + c0 + 8);
    #pragma unroll
    for (int jj = 0; jj < 8; ++jj) { Vt[c0 + jj][j] = a[jj]; Vt[c0 + 8 + jj][j] = bb[jj]; }
  }

  const f32x4 z = {0.f, 0.f, 0.f, 0.f};
  // QK^T: strip rows i in [16w, 16w+16)
  bf16x8 qf[2];
  #pragma unroll
  for (int kc = 0; kc < 2; ++kc) qf[kc] = *(const bf16x8*)(qg + (w * 16 + lr) * 64 + kc * 32 + lk);
  f32x4 accS[4] = {z, z, z, z};
  #pragma unroll
  for (int jt = 0; jt < 4; ++jt)
    #pragma unroll
    for (int kc = 0; kc < 2; ++kc) {
      bf16x8 kf = *(const bf16x8*)(kg + (jt * 16 + lr) * 64 + kc * 32 + lk);
      accS[jt] = __builtin_amdgcn_mfma_f32_16x16x32_bf16(qf[kc], kf, accS[jt], 0, 0, 0);
    }

  // row softmax: row = (l>>4)*4+reg, cols spread over (jt, lr)
  #pragma unroll
  for (int reg = 0; reg < 4; ++reg) {
    float mx = fmaxf(fmaxf(accS[0][reg], accS[1][reg]), fmaxf(accS[2][reg], accS[3][reg]));
    #pragma unroll
    for (int m = 1; m < 16; m <<= 1) mx = fmaxf(mx, __shfl_xor(mx, m, 64));
    float e0 = __expf(accS[0][reg] - mx), e1 = __expf(accS[1][reg] - mx);
    float e2 = __expf(accS[2][reg] - mx), e3 = __expf(accS[3][reg] - mx);
    float sm = e0 + e1 + e2 + e3;
    #pragma unroll
    for (int m = 1; m < 16; m <<= 1) sm += __shfl_xor(sm, m, 64);
    const float rs = 1.f / sm;
    const int row = (l >> 4) * 4 + reg;
    P[w][row][0 * 16 + lr] = f2b(e0 * rs);
    P[w][row][1 * 16 + lr] = f2b(e1 * rs);
    P[w][row][2 * 16 + lr] = f2b(e2 * rs);
    P[w][row][3 * 16 + lr] = f2b(e3 * rs);
  }
  __syncthreads();

  // PV: A = P strip rows (lane&15), B = Vt rows (n) with j contiguous
  bf16x8 pf[2];
  #pragma unroll
  for (int kc = 0; kc < 2; ++kc) pf[kc] = *(const bf16x8*)(&P[w][lr][kc * 32 + lk]);
  f32x4 accY[4] = {z, z, z, z};
  #pragma unroll
  for (int nt = 0; nt < 4; ++nt)
    #pragma unroll
    for (int kc = 0; kc < 2; ++kc) {
      bf16x8 vf = *(const bf16x8*)(&Vt[nt * 16 + lr][kc * 32 + lk]);
      accY[nt] = __builtin_amdgcn_mfma_f32_16x16x32_bf16(pf[kc], vf, accY[nt], 0, 0, 0);
    }

  unsigned short* yg = yout + (size_t)g * 4096;
  #pragma unroll
  for (int nt = 0; nt < 4; ++nt)
    #pragma unroll
    for (int reg = 0; reg < 4; ++reg) {
      const int i = w * 16 + (l >> 4) * 4 + reg;
      yg[i * 64 + nt * 16 + lr] = f2b(accY[nt][reg]);
    }
}

// ---------------- G2b: y [B][CR][S] -> yt [B][S][CR] (bf16) ----------------
__global__ __launch_bounds__(256) void k_yt(const unsigned short* __restrict__ y, unsigned short* __restrict__ yt)
{
  __shared__ unsigned short tile[64][72];
  const int b = blockIdx.z, cr0 = blockIdx.y * 64, s0 = blockIdx.x * 64;
  const int t = threadIdx.x, r = t >> 2, c0 = (t & 3) * 16;
  const unsigned short* src = y + ((size_t)b * 256 + cr0 + r) * 4096 + s0 + c0;
  bf16x8 a = *(const bf16x8*)(src);
  bf16x8 bb = *(const bf16x8*)(src + 8);
  #pragma unroll
  for (int j = 0; j < 8; ++j) { tile[r][c0 + j] = a[j]; tile[r][c0 + 8 + j] = bb[j]; }
  __syncthreads();
  unsigned short* dst = yt + ((size_t)b * 4096 + s0 + r) * 256 + cr0 + c0;
  bf16x8 o0, o1;
  #pragma unroll
  for (int j = 0; j < 8; ++j) { o0[j] = tile[c0 + j][r]; o1[j] = tile[c0 + 8 + j][r]; }
  *(bf16x8*)(dst) = o0;
  *(bf16x8*)(dst + 8) = o1;
}

// ---------------- G3: recon GEMM + BN + residual ----------------
__global__ __launch_bounds__(256) void k_recon(
    const unsigned short* __restrict__ yt, const unsigned short* __restrict__ wrb,
    const float* __restrict__ scale, const float* __restrict__ off2,
    const float* __restrict__ x, float* __restrict__ out)
{
  __shared__ unsigned short lds[2][2][4096];
  const int b = blockIdx.z, o0 = blockIdx.y * 128, s0 = blockIdx.x * 128;
  const int t = threadIdx.x, w = t >> 6, l = t & 63;
  const int wm = w >> 1, wn = w & 1, lr = l & 15, koff = (l >> 4) * 8;

  const unsigned short* Ag = wrb + (size_t)(o0 + (t >> 2)) * 256 + (t & 3) * 8;
  const unsigned short* Bg = yt + ((size_t)b * 4096 + s0 + (t >> 2)) * 256 + (t & 3) * 8;

  const f32x4 z = {0.f, 0.f, 0.f, 0.f};
  f32x4 acc[4][4];
  #pragma unroll
  for (int i = 0; i < 4; ++i)
    #pragma unroll
    for (int j = 0; j < 4; ++j) acc[i][j] = z;

  GL16(Ag, (char*)&lds[0][0][0] + t * 16);
  GL16(Ag + 64 * 256, (char*)&lds[0][0][0] + t * 16 + 4096);
  GL16(Bg, (char*)&lds[0][1][0] + t * 16);
  GL16(Bg + 64 * 256, (char*)&lds[0][1][0] + t * 16 + 4096);

  int cur = 0;
  for (int kt = 0; kt < 8; ++kt) {
    __syncthreads();
    if (kt + 1 < 8) {
      const unsigned short* a2 = Ag + (kt + 1) * 32;
      const unsigned short* b2 = Bg + (kt + 1) * 32;
      GL16(a2, (char*)&lds[cur ^ 1][0][0] + t * 16);
      GL16(a2 + 64 * 256, (char*)&lds[cur ^ 1][0][0] + t * 16 + 4096);
      GL16(b2, (char*)&lds[cur ^ 1][1][0] + t * 16);
      GL16(b2 + 64 * 256, (char*)&lds[cur ^ 1][1][0] + t * 16 + 4096);
    }
    const unsigned short* A = &lds[cur][0][0];
    const unsigned short* Bl = &lds[cur][1][0];
    bf16x8 af[4], bf[4];
    #pragma unroll
    for (int mi = 0; mi < 4; ++mi) af[mi] = *(const bf16x8*)(A + (wm * 64 + mi * 16 + lr) * 32 + koff);
    #pragma unroll
    for (int ni = 0; ni < 4; ++ni) bf[ni] = *(const bf16x8*)(Bl + (wn * 64 + ni * 16 + lr) * 32 + koff);
    #pragma unroll
    for (int mi = 0; mi < 4; ++mi)
      #pragma unroll
      for (int ni = 0; ni < 4; ++ni)
        acc[mi][ni] = __builtin_amdgcn_mfma_f32_16x16x32_bf16(af[mi], bf[ni], acc[mi][ni], 0, 0, 0);
    cur ^= 1;
  }

  // epilogue: out = acc*scale[o] + off2[o] + x  (coalesced along s)
  #pragma unroll
  for (int mi = 0; mi < 4; ++mi) {
    #pragma unroll
    for (int reg = 0; reg < 4; ++reg) {
      const int o = o0 + wm * 64 + mi * 16 + (l >> 4) * 4 + reg;
      const float sc = scale[o], of = off2[o];
      const size_t base = ((size_t)b * 512 + o) * 4096;
      #pragma unroll
      for (int ni = 0; ni < 4; ++ni) {
        const int s = s0 + wn * 64 + ni * 16 + lr;
        const size_t idx = base + s;
        out[idx] = acc[mi][ni][reg] * sc + of + x[idx];
      }
    }
  }
}

extern "C" void kernel_launch(void* const* d_in, const int* in_sizes, int n_in,
                              void* d_out, int out_size, void* d_ws, size_t ws_size,
                              hipStream_t stream)
{
  const float* x     = (const float*)d_in[0];
  const float* Wq    = (const float*)d_in[1];
  const float* bq    = (const float*)d_in[2];
  const float* Wk    = (const float*)d_in[3];
  const float* bk    = (const float*)d_in[4];
  const float* Wv    = (const float*)d_in[5];
  const float* bv    = (const float*)d_in[6];
  const float* Wr    = (const float*)d_in[7];
  const float* br    = (const float*)d_in[8];
  const float* gamma = (const float*)d_in[9];
  const float* beta  = (const float*)d_in[10];
  const float* rm    = (const float*)d_in[11];
  const float* rv    = (const float*)d_in[12];

  char* ws = (char*)d_ws;
  unsigned short* wqkv  = (unsigned short*)(ws + OFF_WQKV);
  unsigned short* wrb   = (unsigned short*)(ws + OFF_WR);
  float* bqkv  = (float*)(ws + OFF_BQKV);
  float* scale = (float*)(ws + OFF_SCALE);
  float* off2  = (float*)(ws + OFF_OFF2);
  unsigned short* xt  = (unsigned short*)(ws + OFF_XT);
  unsigned short* yt  = (unsigned short*)(ws + OFF_YT);
  unsigned short* yb  = (unsigned short*)(ws + OFF_Y);
  unsigned short* qkv = (unsigned short*)(ws + OFF_Q);
  float* out = (float*)d_out;

  hipLaunchKernelGGL(k_prep, dim3(1536), dim3(256), 0, stream,
                     Wq, bq, Wk, bk, Wv, bv, Wr, br, gamma, beta, rm, rv,
                     wqkv, wrb, bqkv, scale, off2);
  hipLaunchKernelGGL(k_xt, dim3(64, 8, 16), dim3(256), 0, stream, x, xt);
  hipLaunchKernelGGL(k_qkv, dim3(32, 6, 16), dim3(256), 0, stream, xt, wqkv, bqkv, qkv);
  hipLaunchKernelGGL(k_attn, dim3(4096), dim3(256), 0, stream, qkv, yb);
  hipLaunchKernelGGL(k_yt, dim3(64, 4, 16), dim3(256), 0, stream, yb, yt);
  hipLaunchKernelGGL(k_recon, dim3(32, 4, 16), dim3(256), 0, stream, yt, wrb, scale, off2, x, out);
}

// Round 2
// 222.730 us; speedup vs baseline: 1.2442x; 1.2442x over previous
//
#include <hip/hip_runtime.h>

// types
typedef __attribute__((ext_vector_type(8))) short bf16x8;
typedef __attribute__((ext_vector_type(4))) float f32x4;

#define DEVI static __device__ __forceinline__

DEVI unsigned short f2b(float f) {
  union { float f; unsigned u; } v; v.f = f;
  unsigned r = v.u + 0x7fffu + ((v.u >> 16) & 1u);
  return (unsigned short)(r >> 16);
}

typedef const __attribute__((address_space(1))) void* gas1_t;
typedef __attribute__((address_space(3))) void* las3_t;
#define GL16(g, l) __builtin_amdgcn_global_load_lds((gas1_t)(g), (las3_t)(l), 16, 0, 0)

#define WAITVM(N) asm volatile("s_waitcnt vmcnt(" #N ")" ::: "memory")
#define WAITLGKM  asm volatile("s_waitcnt lgkmcnt(0)" ::: "memory")

// ---- workspace layout (bytes) ----
#define OFF_WQKV  0ull          // 768*512*2 = 786432
#define OFF_WR    786432ull     // 512*256*2 = 262144
#define OFF_BQKV  1048576ull    // 768*4
#define OFF_SCALE 1051648ull    // 512*4
#define OFF_OFF2  1053696ull    // 512*4
#define OFF_XT    2097152ull    // xt bf16 [16][4096][512] = 64 MiB
#define OFF_YT    2097152ull    // yt bf16 [16][4096][256] = 32 MiB (reuses xt after G1)
#define OFF_Y     35651584ull   // y  bf16 [16][256][4096] = 32 MiB
#define OFF_Q     69206016ull   // qkv bf16: q,k,v each 16777216 u16

// ---------------- P0: weight prep ----------------
__global__ __launch_bounds__(256) void k_prep(
    const float* __restrict__ Wq, const float* __restrict__ bq,
    const float* __restrict__ Wk, const float* __restrict__ bk,
    const float* __restrict__ Wv, const float* __restrict__ bv,
    const float* __restrict__ Wr, const float* __restrict__ br,
    const float* __restrict__ gamma, const float* __restrict__ beta,
    const float* __restrict__ rm, const float* __restrict__ rv,
    unsigned short* __restrict__ wqkv, unsigned short* __restrict__ wrb,
    float* __restrict__ bqkv, float* __restrict__ scale, float* __restrict__ off2)
{
  int i = blockIdx.x * 256 + threadIdx.x;
  if (i < 768 * 512) {
    int o = i >> 9, c = i & 511;
    float v = (o < 256) ? Wq[o * 512 + c] : (o < 512 ? Wk[(o - 256) * 512 + c] : Wv[(o - 512) * 512 + c]);
    wqkv[i] = f2b(v);
  }
  if (i < 512 * 256) wrb[i] = f2b(Wr[i]);
  if (i < 768) bqkv[i] = (i < 256) ? bq[i] : (i < 512 ? bk[i - 256] : bv[i - 512]);
  if (i < 512) {
    float inv = gamma[i] * rsqrtf(rv[i] + 1e-5f);
    scale[i] = inv;
    off2[i] = (br[i] - rm[i]) * inv + beta[i];
  }
}

// ---------------- P1: x [B][C][S] f32 -> xt [B][S][C] bf16 ----------------
__global__ __launch_bounds__(256) void k_xt(const float* __restrict__ x, unsigned short* __restrict__ xt)
{
  __shared__ unsigned short tile[64][72];
  const int b = blockIdx.z, c0 = blockIdx.y * 64, s0 = blockIdx.x * 64;
  const int t = threadIdx.x;
  const int r = t >> 2, cc = (t & 3) * 16;
  const float* src = x + ((size_t)b * 512 + c0 + r) * 4096 + s0 + cc;
  #pragma unroll
  for (int j = 0; j < 16; j += 4) {
    float4 v = *(const float4*)(src + j);
    tile[r][cc + j + 0] = f2b(v.x);
    tile[r][cc + j + 1] = f2b(v.y);
    tile[r][cc + j + 2] = f2b(v.z);
    tile[r][cc + j + 3] = f2b(v.w);
  }
  __syncthreads();
  unsigned short* dst = xt + ((size_t)b * 4096 + s0 + r) * 512 + c0 + cc;
  bf16x8 o0, o1;
  #pragma unroll
  for (int j = 0; j < 8; ++j) { o0[j] = tile[cc + j][r]; o1[j] = tile[cc + 8 + j][r]; }
  *(bf16x8*)(dst) = o0;
  *(bf16x8*)(dst + 8) = o1;
}

// ---------------- G1: QKV GEMM, 4-stage ring, counted vmcnt ----------------
__global__ __launch_bounds__(256) void k_qkv(
    const unsigned short* __restrict__ xt, const unsigned short* __restrict__ wqkv,
    const float* __restrict__ bqkv, unsigned short* __restrict__ qkv)
{
  __shared__ unsigned short lds[4][2][4096];  // 64 KB: [stage][A/B][128*32]
  const int b = blockIdx.z, o0 = blockIdx.y * 128, s0 = blockIdx.x * 128;
  const int t = threadIdx.x, w = t >> 6, l = t & 63;
  const int wm = w >> 1, wn = w & 1, lr = l & 15, koff = (l >> 4) * 8;

  const unsigned short* Ag = wqkv + (size_t)(o0 + (t >> 2)) * 512 + (t & 3) * 8;
  const unsigned short* Bg = xt + ((size_t)b * 4096 + s0 + (t >> 2)) * 512 + (t & 3) * 8;

  const f32x4 z = {0.f, 0.f, 0.f, 0.f};
  f32x4 acc[4][4];
  #pragma unroll
  for (int i = 0; i < 4; ++i)
    #pragma unroll
    for (int j = 0; j < 4; ++j) acc[i][j] = z;

#define STG_Q(st, kt) do { \
    GL16(Ag + (kt) * 32,            (char*)&lds[st][0][0] + t * 16); \
    GL16(Ag + (kt) * 32 + 64 * 512, (char*)&lds[st][0][0] + t * 16 + 4096); \
    GL16(Bg + (kt) * 32,            (char*)&lds[st][1][0] + t * 16); \
    GL16(Bg + (kt) * 32 + 64 * 512, (char*)&lds[st][1][0] + t * 16 + 4096); \
  } while (0)

#define CMP_Q(st) do { \
    const unsigned short* A  = &lds[st][0][0]; \
    const unsigned short* Bl = &lds[st][1][0]; \
    bf16x8 af[4], bfr[4]; \
    _Pragma("unroll") \
    for (int mi = 0; mi < 4; ++mi) af[mi] = *(const bf16x8*)(A + (wm * 64 + mi * 16 + lr) * 32 + koff); \
    _Pragma("unroll") \
    for (int ni = 0; ni < 4; ++ni) bfr[ni] = *(const bf16x8*)(Bl + (wn * 64 + ni * 16 + lr) * 32 + koff); \
    _Pragma("unroll") \
    for (int mi = 0; mi < 4; ++mi) \
      _Pragma("unroll") \
      for (int ni = 0; ni < 4; ++ni) \
        acc[mi][ni] = __builtin_amdgcn_mfma_f32_16x16x32_bf16(af[mi], bfr[ni], acc[mi][ni], 0, 0, 0); \
    WAITLGKM; __builtin_amdgcn_sched_barrier(0); \
  } while (0)

  STG_Q(0, 0); STG_Q(1, 1); STG_Q(2, 2);
  #pragma unroll
  for (int kt = 0; kt < 13; ++kt) {
    WAITVM(8);
    __builtin_amdgcn_s_barrier();
    STG_Q((kt + 3) & 3, kt + 3);
    CMP_Q(kt & 3);
  }
  WAITVM(8); __builtin_amdgcn_s_barrier(); CMP_Q(1);   // kt=13
  WAITVM(4); __builtin_amdgcn_s_barrier(); CMP_Q(2);   // kt=14
  WAITVM(0); __builtin_amdgcn_s_barrier(); CMP_Q(3);   // kt=15

  // epilogue: D row = o, col = s; store bf16 to q/k/v
  #pragma unroll
  for (int mi = 0; mi < 4; ++mi) {
    #pragma unroll
    for (int reg = 0; reg < 4; ++reg) {
      const int o = o0 + wm * 64 + mi * 16 + (l >> 4) * 4 + reg;
      const float bias = bqkv[o];
      const size_t base = (size_t)(o >> 8) * 16777216ull + ((size_t)b * 256 + (o & 255)) * 4096;
      #pragma unroll
      for (int ni = 0; ni < 4; ++ni) {
        const int s = s0 + wn * 64 + ni * 16 + lr;
        qkv[base + s] = f2b(acc[mi][ni][reg] + bias);
      }
    }
  }
#undef STG_Q
#undef CMP_Q
}

// ---------------- G2: per-group attention ----------------
__global__ __launch_bounds__(256) void k_attn(const unsigned short* __restrict__ qkv,
                                              unsigned short* __restrict__ yout)
{
  __shared__ unsigned short Vt[64][80];
  __shared__ unsigned short P[4][16][80];
  const int g = blockIdx.x;
  const unsigned short* qg = qkv + (size_t)g * 4096;
  const unsigned short* kg = qkv + 16777216ull + (size_t)g * 4096;
  const unsigned short* vg = qkv + 33554432ull + (size_t)g * 4096;
  const int t = threadIdx.x, w = t >> 6, l = t & 63;
  const int lr = l & 15, lk = (l >> 4) * 8;

  {
    const int j = t >> 2, c0 = (t & 3) * 16;
    bf16x8 a = *(const bf16x8*)(vg + j * 64 + c0);
    bf16x8 bb = *(const bf16x8*)(vg + j * 64 + c0 + 8);
    #pragma unroll
    for (int jj = 0; jj < 8; ++jj) { Vt[c0 + jj][j] = a[jj]; Vt[c0 + 8 + jj][j] = bb[jj]; }
  }

  const f32x4 z = {0.f, 0.f, 0.f, 0.f};
  bf16x8 qf[2];
  #pragma unroll
  for (int kc = 0; kc < 2; ++kc) qf[kc] = *(const bf16x8*)(qg + (w * 16 + lr) * 64 + kc * 32 + lk);
  f32x4 accS[4] = {z, z, z, z};
  #pragma unroll
  for (int jt = 0; jt < 4; ++jt)
    #pragma unroll
    for (int kc = 0; kc < 2; ++kc) {
      bf16x8 kf = *(const bf16x8*)(kg + (jt * 16 + lr) * 64 + kc * 32 + lk);
      accS[jt] = __builtin_amdgcn_mfma_f32_16x16x32_bf16(qf[kc], kf, accS[jt], 0, 0, 0);
    }

  #pragma unroll
  for (int reg = 0; reg < 4; ++reg) {
    float mx = fmaxf(fmaxf(accS[0][reg], accS[1][reg]), fmaxf(accS[2][reg], accS[3][reg]));
    #pragma unroll
    for (int m = 1; m < 16; m <<= 1) mx = fmaxf(mx, __shfl_xor(mx, m, 64));
    float e0 = __expf(accS[0][reg] - mx), e1 = __expf(accS[1][reg] - mx);
    float e2 = __expf(accS[2][reg] - mx), e3 = __expf(accS[3][reg] - mx);
    float sm = e0 + e1 + e2 + e3;
    #pragma unroll
    for (int m = 1; m < 16; m <<= 1) sm += __shfl_xor(sm, m, 64);
    const float rs = 1.f / sm;
    const int row = (l >> 4) * 4 + reg;
    P[w][row][0 * 16 + lr] = f2b(e0 * rs);
    P[w][row][1 * 16 + lr] = f2b(e1 * rs);
    P[w][row][2 * 16 + lr] = f2b(e2 * rs);
    P[w][row][3 * 16 + lr] = f2b(e3 * rs);
  }
  __syncthreads();

  bf16x8 pf[2];
  #pragma unroll
  for (int kc = 0; kc < 2; ++kc) pf[kc] = *(const bf16x8*)(&P[w][lr][kc * 32 + lk]);
  f32x4 accY[4] = {z, z, z, z};
  #pragma unroll
  for (int nt = 0; nt < 4; ++nt)
    #pragma unroll
    for (int kc = 0; kc < 2; ++kc) {
      bf16x8 vf = *(const bf16x8*)(&Vt[nt * 16 + lr][kc * 32 + lk]);
      accY[nt] = __builtin_amdgcn_mfma_f32_16x16x32_bf16(pf[kc], vf, accY[nt], 0, 0, 0);
    }

  unsigned short* yg = yout + (size_t)g * 4096;
  #pragma unroll
  for (int nt = 0; nt < 4; ++nt)
    #pragma unroll
    for (int reg = 0; reg < 4; ++reg) {
      const int i = w * 16 + (l >> 4) * 4 + reg;
      yg[i * 64 + nt * 16 + lr] = f2b(accY[nt][reg]);
    }
}

// ---------------- G2b: y [B][CR][S] -> yt [B][S][CR] ----------------
__global__ __launch_bounds__(256) void k_yt(const unsigned short* __restrict__ y, unsigned short* __restrict__ yt)
{
  __shared__ unsigned short tile[64][72];
  const int b = blockIdx.z, cr0 = blockIdx.y * 64, s0 = blockIdx.x * 64;
  const int t = threadIdx.x, r = t >> 2, c0 = (t & 3) * 16;
  const unsigned short* src = y + ((size_t)b * 256 + cr0 + r) * 4096 + s0 + c0;
  bf16x8 a = *(const bf16x8*)(src);
  bf16x8 bb = *(const bf16x8*)(src + 8);
  #pragma unroll
  for (int j = 0; j < 8; ++j) { tile[r][c0 + j] = a[j]; tile[r][c0 + 8 + j] = bb[j]; }
  __syncthreads();
  unsigned short* dst = yt + ((size_t)b * 4096 + s0 + r) * 256 + cr0 + c0;
  bf16x8 o0, o1;
  #pragma unroll
  for (int j = 0; j < 8; ++j) { o0[j] = tile[c0 + j][r]; o1[j] = tile[c0 + 8 + j][r]; }
  *(bf16x8*)(dst) = o0;
  *(bf16x8*)(dst + 8) = o1;
}

// ---------------- G3: recon GEMM + BN + residual, 4-stage ring ----------------
__global__ __launch_bounds__(256) void k_recon(
    const unsigned short* __restrict__ yt, const unsigned short* __restrict__ wrb,
    const float* __restrict__ scale, const float* __restrict__ off2,
    const float* __restrict__ x, float* __restrict__ out)
{
  __shared__ unsigned short lds[4][2][4096];  // 64 KB
  const int b = blockIdx.z, o0 = blockIdx.y * 128, s0 = blockIdx.x * 128;
  const int t = threadIdx.x, w = t >> 6, l = t & 63;
  const int wm = w >> 1, wn = w & 1, lr = l & 15, koff = (l >> 4) * 8;

  const unsigned short* Ag = wrb + (size_t)(o0 + (t >> 2)) * 256 + (t & 3) * 8;
  const unsigned short* Bg = yt + ((size_t)b * 4096 + s0 + (t >> 2)) * 256 + (t & 3) * 8;

  const f32x4 z = {0.f, 0.f, 0.f, 0.f};
  f32x4 acc[4][4];
  #pragma unroll
  for (int i = 0; i < 4; ++i)
    #pragma unroll
    for (int j = 0; j < 4; ++j) acc[i][j] = z;

#define STG_R(st, kt) do { \
    GL16(Ag + (kt) * 32,            (char*)&lds[st][0][0] + t * 16); \
    GL16(Ag + (kt) * 32 + 64 * 256, (char*)&lds[st][0][0] + t * 16 + 4096); \
    GL16(Bg + (kt) * 32,            (char*)&lds[st][1][0] + t * 16); \
    GL16(Bg + (kt) * 32 + 64 * 256, (char*)&lds[st][1][0] + t * 16 + 4096); \
  } while (0)

#define CMP_R(st) do { \
    const unsigned short* A  = &lds[st][0][0]; \
    const unsigned short* Bl = &lds[st][1][0]; \
    bf16x8 af[4], bfr[4]; \
    _Pragma("unroll") \
    for (int mi = 0; mi < 4; ++mi) af[mi] = *(const bf16x8*)(A + (wm * 64 + mi * 16 + lr) * 32 + koff); \
    _Pragma("unroll") \
    for (int ni = 0; ni < 4; ++ni) bfr[ni] = *(const bf16x8*)(Bl + (wn * 64 + ni * 16 + lr) * 32 + koff); \
    _Pragma("unroll") \
    for (int mi = 0; mi < 4; ++mi) \
      _Pragma("unroll") \
      for (int ni = 0; ni < 4; ++ni) \
        acc[mi][ni] = __builtin_amdgcn_mfma_f32_16x16x32_bf16(af[mi], bfr[ni], acc[mi][ni], 0, 0, 0); \
    WAITLGKM; __builtin_amdgcn_sched_barrier(0); \
  } while (0)

  STG_R(0, 0); STG_R(1, 1); STG_R(2, 2);
  #pragma unroll
  for (int kt = 0; kt < 5; ++kt) {
    WAITVM(8);
    __builtin_amdgcn_s_barrier();
    STG_R((kt + 3) & 3, kt + 3);
    CMP_R(kt & 3);
  }
  WAITVM(8); __builtin_amdgcn_s_barrier(); CMP_R(1);   // kt=5
  WAITVM(4); __builtin_amdgcn_s_barrier(); CMP_R(2);   // kt=6
  WAITVM(0); __builtin_amdgcn_s_barrier(); CMP_R(3);   // kt=7

  // epilogue: out = acc*scale[o] + off2[o] + x
  #pragma unroll
  for (int mi = 0; mi < 4; ++mi) {
    #pragma unroll
    for (int reg = 0; reg < 4; ++reg) {
      const int o = o0 + wm * 64 + mi * 16 + (l >> 4) * 4 + reg;
      const float sc = scale[o], of = off2[o];
      const size_t base = ((size_t)b * 512 + o) * 4096;
      #pragma unroll
      for (int ni = 0; ni < 4; ++ni) {
        const int s = s0 + wn * 64 + ni * 16 + lr;
        const size_t idx = base + s;
        out[idx] = acc[mi][ni][reg] * sc + of + x[idx];
      }
    }
  }
#undef STG_R
#undef CMP_R
}

extern "C" void kernel_launch(void* const* d_in, const int* in_sizes, int n_in,
                              void* d_out, int out_size, void* d_ws, size_t ws_size,
                              hipStream_t stream)
{
  const float* x     = (const float*)d_in[0];
  const float* Wq    = (const float*)d_in[1];
  const float* bq    = (const float*)d_in[2];
  const float* Wk    = (const float*)d_in[3];
  const float* bk    = (const float*)d_in[4];
  const float* Wv    = (const float*)d_in[5];
  const float* bv    = (const float*)d_in[6];
  const float* Wr    = (const float*)d_in[7];
  const float* br    = (const float*)d_in[8];
  const float* gamma = (const float*)d_in[9];
  const float* beta  = (const float*)d_in[10];
  const float* rm    = (const float*)d_in[11];
  const float* rv    = (const float*)d_in[12];

  char* ws = (char*)d_ws;
  unsigned short* wqkv  = (unsigned short*)(ws + OFF_WQKV);
  unsigned short* wrb   = (unsigned short*)(ws + OFF_WR);
  float* bqkv  = (float*)(ws + OFF_BQKV);
  float* scale = (float*)(ws + OFF_SCALE);
  float* off2  = (float*)(ws + OFF_OFF2);
  unsigned short* xt  = (unsigned short*)(ws + OFF_XT);
  unsigned short* yt  = (unsigned short*)(ws + OFF_YT);
  unsigned short* yb  = (unsigned short*)(ws + OFF_Y);
  unsigned short* qkv = (unsigned short*)(ws + OFF_Q);
  float* out = (float*)d_out;

  hipLaunchKernelGGL(k_prep, dim3(1536), dim3(256), 0, stream,
                     Wq, bq, Wk, bk, Wv, bv, Wr, br, gamma, beta, rm, rv,
                     wqkv, wrb, bqkv, scale, off2);
  hipLaunchKernelGGL(k_xt, dim3(64, 8, 16), dim3(256), 0, stream, x, xt);
  hipLaunchKernelGGL(k_qkv, dim3(32, 6, 16), dim3(256), 0, stream, xt, wqkv, bqkv, qkv);
  hipLaunchKernelGGL(k_attn, dim3(4096), dim3(256), 0, stream, qkv, yb);
  hipLaunchKernelGGL(k_yt, dim3(64, 4, 16), dim3(256), 0, stream, yb, yt);
  hipLaunchKernelGGL(k_recon, dim3(32, 4, 16), dim3(256), 0, stream, yt, wrb, scale, off2, x, out);
}

// Round 3
// 212.471 us; speedup vs baseline: 1.3042x; 1.0483x over previous
//
#include <hip/hip_runtime.h>

// types
typedef __attribute__((ext_vector_type(8))) short bf16x8;
typedef __attribute__((ext_vector_type(4))) float f32x4;

#define DEVI static __device__ __forceinline__

DEVI unsigned short f2b(float f) {
  union { float f; unsigned u; } v; v.f = f;
  unsigned r = v.u + 0x7fffu + ((v.u >> 16) & 1u);
  return (unsigned short)(r >> 16);
}

typedef const __attribute__((address_space(1))) void* gas1_t;
typedef __attribute__((address_space(3))) void* las3_t;
#define GL16(g, l) __builtin_amdgcn_global_load_lds((gas1_t)(g), (las3_t)(l), 16, 0, 0)

#define WAITVM(N) asm volatile("s_waitcnt vmcnt(" #N ")" ::: "memory")
#define WAITLGKM  asm volatile("s_waitcnt lgkmcnt(0)" ::: "memory")

// ---- workspace layout (bytes) ----
#define OFF_WQKV  0ull          // 768*512*2 = 786432
#define OFF_WR    786432ull     // 512*256*2 = 262144
#define OFF_BQKV  1048576ull    // 768*4
#define OFF_SCALE 1051648ull    // 512*4
#define OFF_OFF2  1053696ull    // 512*4
#define OFF_XT    2097152ull    // xt bf16 [16][4096][512] = 64 MiB
#define OFF_YT    2097152ull    // yt bf16 [16][4096][256] = 32 MiB (reuses xt after G1)
#define OFF_Y     35651584ull   // y  bf16 [16][256][4096] = 32 MiB
#define OFF_Q     69206016ull   // qkv bf16: q,k,v each 16777216 u16

// ---------------- P0: weight prep ----------------
__global__ __launch_bounds__(256) void k_prep(
    const float* __restrict__ Wq, const float* __restrict__ bq,
    const float* __restrict__ Wk, const float* __restrict__ bk,
    const float* __restrict__ Wv, const float* __restrict__ bv,
    const float* __restrict__ Wr, const float* __restrict__ br,
    const float* __restrict__ gamma, const float* __restrict__ beta,
    const float* __restrict__ rm, const float* __restrict__ rv,
    unsigned short* __restrict__ wqkv, unsigned short* __restrict__ wrb,
    float* __restrict__ bqkv, float* __restrict__ scale, float* __restrict__ off2)
{
  int i = blockIdx.x * 256 + threadIdx.x;
  if (i < 768 * 512) {
    int o = i >> 9, c = i & 511;
    float v = (o < 256) ? Wq[o * 512 + c] : (o < 512 ? Wk[(o - 256) * 512 + c] : Wv[(o - 512) * 512 + c]);
    wqkv[i] = f2b(v);
  }
  if (i < 512 * 256) wrb[i] = f2b(Wr[i]);
  if (i < 768) bqkv[i] = (i < 256) ? bq[i] : (i < 512 ? bk[i - 256] : bv[i - 512]);
  if (i < 512) {
    float inv = gamma[i] * rsqrtf(rv[i] + 1e-5f);
    scale[i] = inv;
    off2[i] = (br[i] - rm[i]) * inv + beta[i];
  }
}

// ---------------- P1: x [B][C][S] f32 -> xt [B][S][C] bf16 ----------------
__global__ __launch_bounds__(256) void k_xt(const float* __restrict__ x, unsigned short* __restrict__ xt)
{
  __shared__ unsigned short tile[64][72];
  const int b = blockIdx.z, c0 = blockIdx.y * 64, s0 = blockIdx.x * 64;
  const int t = threadIdx.x;
  const int r = t >> 2, cc = (t & 3) * 16;
  const float* src = x + ((size_t)b * 512 + c0 + r) * 4096 + s0 + cc;
  #pragma unroll
  for (int j = 0; j < 16; j += 4) {
    float4 v = *(const float4*)(src + j);
    tile[r][cc + j + 0] = f2b(v.x);
    tile[r][cc + j + 1] = f2b(v.y);
    tile[r][cc + j + 2] = f2b(v.z);
    tile[r][cc + j + 3] = f2b(v.w);
  }
  __syncthreads();
  unsigned short* dst = xt + ((size_t)b * 4096 + s0 + r) * 512 + c0 + cc;
  bf16x8 o0, o1;
  #pragma unroll
  for (int j = 0; j < 8; ++j) { o0[j] = tile[cc + j][r]; o1[j] = tile[cc + 8 + j][r]; }
  *(bf16x8*)(dst) = o0;
  *(bf16x8*)(dst + 8) = o1;
}

// ============== shared GEMM machinery: 128x128 tile, BK=64, ring-2, swizzled LDS ==============
// LDS per stage per matrix: [128 rows][64 k] bf16, row = 128B.
// Read swizzle: elem kb' = kb ^ ((row&7)*8)  (8-elem chunks XOR'd by row&7 -> 32-bank coverage).
// Staging pre-swizzles GLOBAL source chunk: c' = (t&7) ^ ((t>>3)&7), GL16 dest stays linear.

// ---------------- G1: QKV GEMM ----------------
__global__ __launch_bounds__(256) void k_qkv(
    const unsigned short* __restrict__ xt, const unsigned short* __restrict__ wqkv,
    const float* __restrict__ bqkv, unsigned short* __restrict__ qkv)
{
  __shared__ unsigned short lds[2][2][8192];  // 64 KB: [stage][A/B][128*64]
  const int b = blockIdx.z, o0 = blockIdx.y * 128, s0 = blockIdx.x * 128;
  const int t = threadIdx.x, w = t >> 6, l = t & 63;
  const int wm = w >> 1, wn = w & 1, lr = l & 15;
  const int lkE = (l >> 4) * 8;          // k-elem offset within 32-chunk
  const int swE = (lr & 7) * 8;          // read-side swizzle (row&7 == lr&7 for all fragment rows)
  const int cp = (t & 7) ^ ((t >> 3) & 7);  // staging source chunk pre-swizzle

  const unsigned short* Ag = wqkv + (size_t)(o0 + (t >> 3)) * 512 + cp * 8;
  const unsigned short* Bg = xt + ((size_t)b * 4096 + s0 + (t >> 3)) * 512 + cp * 8;

  const f32x4 z = {0.f, 0.f, 0.f, 0.f};
  f32x4 acc[4][4];
  #pragma unroll
  for (int i = 0; i < 4; ++i)
    #pragma unroll
    for (int j = 0; j < 4; ++j) acc[i][j] = z;

#define STG_Q(st, kt) do { \
    _Pragma("unroll") \
    for (int j = 0; j < 4; ++j) { \
      GL16(Ag + (kt) * 64 + j * 32 * 512, (char*)&lds[st][0][0] + j * 4096 + t * 16); \
      GL16(Bg + (kt) * 64 + j * 32 * 512, (char*)&lds[st][1][0] + j * 4096 + t * 16); \
    } \
  } while (0)

#define CMP_Q(st) do { \
    const unsigned short* A  = &lds[st][0][0]; \
    const unsigned short* Bl = &lds[st][1][0]; \
    _Pragma("unroll") \
    for (int kc = 0; kc < 2; ++kc) { \
      const int kidx = (kc * 32 + lkE) ^ swE; \
      bf16x8 af[4], bfr[4]; \
      _Pragma("unroll") \
      for (int mi = 0; mi < 4; ++mi) af[mi] = *(const bf16x8*)(A + (wm * 64 + mi * 16 + lr) * 64 + kidx); \
      _Pragma("unroll") \
      for (int ni = 0; ni < 4; ++ni) bfr[ni] = *(const bf16x8*)(Bl + (wn * 64 + ni * 16 + lr) * 64 + kidx); \
      _Pragma("unroll") \
      for (int mi = 0; mi < 4; ++mi) \
        _Pragma("unroll") \
        for (int ni = 0; ni < 4; ++ni) \
          acc[mi][ni] = __builtin_amdgcn_mfma_f32_16x16x32_bf16(af[mi], bfr[ni], acc[mi][ni], 0, 0, 0); \
    } \
    WAITLGKM; __builtin_amdgcn_sched_barrier(0); \
  } while (0)

  STG_Q(0, 0); STG_Q(1, 1);
  #pragma unroll
  for (int kt = 0; kt < 7; ++kt) {
    WAITVM(8);
    __builtin_amdgcn_s_barrier();
    CMP_Q(kt & 1);
    if (kt + 2 < 8) {
      __builtin_amdgcn_s_barrier();
      STG_Q(kt & 1, kt + 2);
    }
  }
  WAITVM(0);
  __builtin_amdgcn_s_barrier();
  CMP_Q(1);   // kt=7

  // epilogue: D row = o, col = s; store bf16 to q/k/v
  #pragma unroll
  for (int mi = 0; mi < 4; ++mi) {
    #pragma unroll
    for (int reg = 0; reg < 4; ++reg) {
      const int o = o0 + wm * 64 + mi * 16 + (l >> 4) * 4 + reg;
      const float bias = bqkv[o];
      const size_t base = (size_t)(o >> 8) * 16777216ull + ((size_t)b * 256 + (o & 255)) * 4096;
      #pragma unroll
      for (int ni = 0; ni < 4; ++ni) {
        const int s = s0 + wn * 64 + ni * 16 + lr;
        qkv[base + s] = f2b(acc[mi][ni][reg] + bias);
      }
    }
  }
#undef STG_Q
#undef CMP_Q
}

// ---------------- G2: per-group attention ----------------
__global__ __launch_bounds__(256) void k_attn(const unsigned short* __restrict__ qkv,
                                              unsigned short* __restrict__ yout)
{
  __shared__ unsigned short Vt[64][80];
  __shared__ unsigned short P[4][16][80];
  const int g = blockIdx.x;
  const unsigned short* qg = qkv + (size_t)g * 4096;
  const unsigned short* kg = qkv + 16777216ull + (size_t)g * 4096;
  const unsigned short* vg = qkv + 33554432ull + (size_t)g * 4096;
  const int t = threadIdx.x, w = t >> 6, l = t & 63;
  const int lr = l & 15, lk = (l >> 4) * 8;

  {
    const int j = t >> 2, c0 = (t & 3) * 16;
    bf16x8 a = *(const bf16x8*)(vg + j * 64 + c0);
    bf16x8 bb = *(const bf16x8*)(vg + j * 64 + c0 + 8);
    #pragma unroll
    for (int jj = 0; jj < 8; ++jj) { Vt[c0 + jj][j] = a[jj]; Vt[c0 + 8 + jj][j] = bb[jj]; }
  }

  const f32x4 z = {0.f, 0.f, 0.f, 0.f};
  bf16x8 qf[2];
  #pragma unroll
  for (int kc = 0; kc < 2; ++kc) qf[kc] = *(const bf16x8*)(qg + (w * 16 + lr) * 64 + kc * 32 + lk);
  f32x4 accS[4] = {z, z, z, z};
  #pragma unroll
  for (int jt = 0; jt < 4; ++jt)
    #pragma unroll
    for (int kc = 0; kc < 2; ++kc) {
      bf16x8 kf = *(const bf16x8*)(kg + (jt * 16 + lr) * 64 + kc * 32 + lk);
      accS[jt] = __builtin_amdgcn_mfma_f32_16x16x32_bf16(qf[kc], kf, accS[jt], 0, 0, 0);
    }

  #pragma unroll
  for (int reg = 0; reg < 4; ++reg) {
    float mx = fmaxf(fmaxf(accS[0][reg], accS[1][reg]), fmaxf(accS[2][reg], accS[3][reg]));
    #pragma unroll
    for (int m = 1; m < 16; m <<= 1) mx = fmaxf(mx, __shfl_xor(mx, m, 64));
    float e0 = __expf(accS[0][reg] - mx), e1 = __expf(accS[1][reg] - mx);
    float e2 = __expf(accS[2][reg] - mx), e3 = __expf(accS[3][reg] - mx);
    float sm = e0 + e1 + e2 + e3;
    #pragma unroll
    for (int m = 1; m < 16; m <<= 1) sm += __shfl_xor(sm, m, 64);
    const float rs = 1.f / sm;
    const int row = (l >> 4) * 4 + reg;
    P[w][row][0 * 16 + lr] = f2b(e0 * rs);
    P[w][row][1 * 16 + lr] = f2b(e1 * rs);
    P[w][row][2 * 16 + lr] = f2b(e2 * rs);
    P[w][row][3 * 16 + lr] = f2b(e3 * rs);
  }
  __syncthreads();

  bf16x8 pf[2];
  #pragma unroll
  for (int kc = 0; kc < 2; ++kc) pf[kc] = *(const bf16x8*)(&P[w][lr][kc * 32 + lk]);
  f32x4 accY[4] = {z, z, z, z};
  #pragma unroll
  for (int nt = 0; nt < 4; ++nt)
    #pragma unroll
    for (int kc = 0; kc < 2; ++kc) {
      bf16x8 vf = *(const bf16x8*)(&Vt[nt * 16 + lr][kc * 32 + lk]);
      accY[nt] = __builtin_amdgcn_mfma_f32_16x16x32_bf16(pf[kc], vf, accY[nt], 0, 0, 0);
    }

  unsigned short* yg = yout + (size_t)g * 4096;
  #pragma unroll
  for (int nt = 0; nt < 4; ++nt)
    #pragma unroll
    for (int reg = 0; reg < 4; ++reg) {
      const int i = w * 16 + (l >> 4) * 4 + reg;
      yg[i * 64 + nt * 16 + lr] = f2b(accY[nt][reg]);
    }
}

// ---------------- G2b: y [B][CR][S] -> yt [B][S][CR] ----------------
__global__ __launch_bounds__(256) void k_yt(const unsigned short* __restrict__ y, unsigned short* __restrict__ yt)
{
  __shared__ unsigned short tile[64][72];
  const int b = blockIdx.z, cr0 = blockIdx.y * 64, s0 = blockIdx.x * 64;
  const int t = threadIdx.x, r = t >> 2, c0 = (t & 3) * 16;
  const unsigned short* src = y + ((size_t)b * 256 + cr0 + r) * 4096 + s0 + c0;
  bf16x8 a = *(const bf16x8*)(src);
  bf16x8 bb = *(const bf16x8*)(src + 8);
  #pragma unroll
  for (int j = 0; j < 8; ++j) { tile[r][c0 + j] = a[j]; tile[r][c0 + 8 + j] = bb[j]; }
  __syncthreads();
  unsigned short* dst = yt + ((size_t)b * 4096 + s0 + r) * 256 + cr0 + c0;
  bf16x8 o0, o1;
  #pragma unroll
  for (int j = 0; j < 8; ++j) { o0[j] = tile[c0 + j][r]; o1[j] = tile[c0 + 8 + j][r]; }
  *(bf16x8*)(dst) = o0;
  *(bf16x8*)(dst + 8) = o1;
}

// ---------------- G3: recon GEMM + BN + residual ----------------
__global__ __launch_bounds__(256) void k_recon(
    const unsigned short* __restrict__ yt, const unsigned short* __restrict__ wrb,
    const float* __restrict__ scale, const float* __restrict__ off2,
    const float* __restrict__ x, float* __restrict__ out)
{
  __shared__ unsigned short lds[2][2][8192];  // 64 KB
  const int b = blockIdx.z, o0 = blockIdx.y * 128, s0 = blockIdx.x * 128;
  const int t = threadIdx.x, w = t >> 6, l = t & 63;
  const int wm = w >> 1, wn = w & 1, lr = l & 15;
  const int lkE = (l >> 4) * 8;
  const int swE = (lr & 7) * 8;
  const int cp = (t & 7) ^ ((t >> 3) & 7);

  const unsigned short* Ag = wrb + (size_t)(o0 + (t >> 3)) * 256 + cp * 8;
  const unsigned short* Bg = yt + ((size_t)b * 4096 + s0 + (t >> 3)) * 256 + cp * 8;

  const f32x4 z = {0.f, 0.f, 0.f, 0.f};
  f32x4 acc[4][4];
  #pragma unroll
  for (int i = 0; i < 4; ++i)
    #pragma unroll
    for (int j = 0; j < 4; ++j) acc[i][j] = z;

#define STG_R(st, kt) do { \
    _Pragma("unroll") \
    for (int j = 0; j < 4; ++j) { \
      GL16(Ag + (kt) * 64 + j * 32 * 256, (char*)&lds[st][0][0] + j * 4096 + t * 16); \
      GL16(Bg + (kt) * 64 + j * 32 * 256, (char*)&lds[st][1][0] + j * 4096 + t * 16); \
    } \
  } while (0)

#define CMP_R(st) do { \
    const unsigned short* A  = &lds[st][0][0]; \
    const unsigned short* Bl = &lds[st][1][0]; \
    _Pragma("unroll") \
    for (int kc = 0; kc < 2; ++kc) { \
      const int kidx = (kc * 32 + lkE) ^ swE; \
      bf16x8 af[4], bfr[4]; \
      _Pragma("unroll") \
      for (int mi = 0; mi < 4; ++mi) af[mi] = *(const bf16x8*)(A + (wm * 64 + mi * 16 + lr) * 64 + kidx); \
      _Pragma("unroll") \
      for (int ni = 0; ni < 4; ++ni) bfr[ni] = *(const bf16x8*)(Bl + (wn * 64 + ni * 16 + lr) * 64 + kidx); \
      _Pragma("unroll") \
      for (int mi = 0; mi < 4; ++mi) \
        _Pragma("unroll") \
        for (int ni = 0; ni < 4; ++ni) \
          acc[mi][ni] = __builtin_amdgcn_mfma_f32_16x16x32_bf16(af[mi], bfr[ni], acc[mi][ni], 0, 0, 0); \
    } \
    WAITLGKM; __builtin_amdgcn_sched_barrier(0); \
  } while (0)

  STG_R(0, 0); STG_R(1, 1);
  #pragma unroll
  for (int kt = 0; kt < 3; ++kt) {
    WAITVM(8);
    __builtin_amdgcn_s_barrier();
    CMP_R(kt & 1);
    if (kt + 2 < 4) {
      __builtin_amdgcn_s_barrier();
      STG_R(kt & 1, kt + 2);
    }
  }
  WAITVM(0);
  __builtin_amdgcn_s_barrier();
  CMP_R(1);   // kt=3

  // epilogue: out = acc*scale[o] + off2[o] + x
  #pragma unroll
  for (int mi = 0; mi < 4; ++mi) {
    #pragma unroll
    for (int reg = 0; reg < 4; ++reg) {
      const int o = o0 + wm * 64 + mi * 16 + (l >> 4) * 4 + reg;
      const float sc = scale[o], of = off2[o];
      const size_t base = ((size_t)b * 512 + o) * 4096;
      #pragma unroll
      for (int ni = 0; ni < 4; ++ni) {
        const int s = s0 + wn * 64 + ni * 16 + lr;
        const size_t idx = base + s;
        out[idx] = acc[mi][ni][reg] * sc + of + x[idx];
      }
    }
  }
#undef STG_R
#undef CMP_R
}

extern "C" void kernel_launch(void* const* d_in, const int* in_sizes, int n_in,
                              void* d_out, int out_size, void* d_ws, size_t ws_size,
                              hipStream_t stream)
{
  const float* x     = (const float*)d_in[0];
  const float* Wq    = (const float*)d_in[1];
  const float* bq    = (const float*)d_in[2];
  const float* Wk    = (const float*)d_in[3];
  const float* bk    = (const float*)d_in[4];
  const float* Wv    = (const float*)d_in[5];
  const float* bv    = (const float*)d_in[6];
  const float* Wr    = (const float*)d_in[7];
  const float* br    = (const float*)d_in[8];
  const float* gamma = (const float*)d_in[9];
  const float* beta  = (const float*)d_in[10];
  const float* rm    = (const float*)d_in[11];
  const float* rv    = (const float*)d_in[12];

  char* ws = (char*)d_ws;
  unsigned short* wqkv  = (unsigned short*)(ws + OFF_WQKV);
  unsigned short* wrb   = (unsigned short*)(ws + OFF_WR);
  float* bqkv  = (float*)(ws + OFF_BQKV);
  float* scale = (float*)(ws + OFF_SCALE);
  float* off2  = (float*)(ws + OFF_OFF2);
  unsigned short* xt  = (unsigned short*)(ws + OFF_XT);
  unsigned short* yt  = (unsigned short*)(ws + OFF_YT);
  unsigned short* yb  = (unsigned short*)(ws + OFF_Y);
  unsigned short* qkv = (unsigned short*)(ws + OFF_Q);
  float* out = (float*)d_out;

  hipLaunchKernelGGL(k_prep, dim3(1536), dim3(256), 0, stream,
                     Wq, bq, Wk, bk, Wv, bv, Wr, br, gamma, beta, rm, rv,
                     wqkv, wrb, bqkv, scale, off2);
  hipLaunchKernelGGL(k_xt, dim3(64, 8, 16), dim3(256), 0, stream, x, xt);
  hipLaunchKernelGGL(k_qkv, dim3(32, 6, 16), dim3(256), 0, stream, xt, wqkv, bqkv, qkv);
  hipLaunchKernelGGL(k_attn, dim3(4096), dim3(256), 0, stream, qkv, yb);
  hipLaunchKernelGGL(k_yt, dim3(64, 4, 16), dim3(256), 0, stream, yb, yt);
  hipLaunchKernelGGL(k_recon, dim3(32, 4, 16), dim3(256), 0, stream, yt, wrb, scale, off2, x, out);
}

// Round 4
// 201.725 us; speedup vs baseline: 1.3737x; 1.0533x over previous
//
#include <hip/hip_runtime.h>

// types
typedef __attribute__((ext_vector_type(8))) short bf16x8;
typedef __attribute__((ext_vector_type(4))) float f32x4;

#define DEVI static __device__ __forceinline__

DEVI unsigned short f2b(float f) {
  union { float f; unsigned u; } v; v.f = f;
  unsigned r = v.u + 0x7fffu + ((v.u >> 16) & 1u);
  return (unsigned short)(r >> 16);
}

typedef const __attribute__((address_space(1))) void* gas1_t;
typedef __attribute__((address_space(3))) void* las3_t;
#define GL16(g, l) __builtin_amdgcn_global_load_lds((gas1_t)(g), (las3_t)(l), 16, 0, 0)

#define WAITVM(N) asm volatile("s_waitcnt vmcnt(" #N ")" ::: "memory")
#define WAITLGKM  asm volatile("s_waitcnt lgkmcnt(0)" ::: "memory")
#define SCHEDBAR  __builtin_amdgcn_sched_barrier(0)

// ---- workspace layout (bytes) ----
#define OFF_WQKV  0ull          // 768*512*2
#define OFF_WR    786432ull     // 512*256*2
#define OFF_BQKV  1048576ull
#define OFF_SCALE 1051648ull
#define OFF_OFF2  1053696ull
#define OFF_XT    2097152ull    // xt bf16 [16][4096][512] = 64 MiB
#define OFF_Y     35651584ull   // y bf16 [16][256][4096] = 32 MiB (overlaps xt tail; attn runs after qkv)
#define OFF_Q     69206016ull   // qkv bf16: q,k,v each 16777216 u16

// ---------------- P1: x [B][C][S] f32 -> xt [B][S][C] bf16  (+ fused weight prep) ----------------
__global__ __launch_bounds__(256) void k_xt(
    const float* __restrict__ x, unsigned short* __restrict__ xt,
    const float* __restrict__ Wq, const float* __restrict__ bq,
    const float* __restrict__ Wk, const float* __restrict__ bk,
    const float* __restrict__ Wv, const float* __restrict__ bv,
    const float* __restrict__ Wr, const float* __restrict__ br,
    const float* __restrict__ gamma, const float* __restrict__ beta,
    const float* __restrict__ rm, const float* __restrict__ rv,
    unsigned short* __restrict__ wqkv, unsigned short* __restrict__ wrb,
    float* __restrict__ bqkv, float* __restrict__ scale, float* __restrict__ off2)
{
  __shared__ unsigned short tile[64][72];
  const int t = threadIdx.x;
  const int bid = blockIdx.x + blockIdx.y * 64 + blockIdx.z * 512;

  // fused prep (first 1536 blocks handle 256 elements each)
  if (bid < 1536) {
    int i = bid * 256 + t;
    if (i < 768 * 512) {
      int o = i >> 9, c = i & 511;
      float v = (o < 256) ? Wq[o * 512 + c] : (o < 512 ? Wk[(o - 256) * 512 + c] : Wv[(o - 512) * 512 + c]);
      wqkv[i] = f2b(v);
    }
    if (i < 512 * 256) wrb[i] = f2b(Wr[i]);
    if (i < 768) bqkv[i] = (i < 256) ? bq[i] : (i < 512 ? bk[i - 256] : bv[i - 512]);
    if (i < 512) {
      float inv = gamma[i] * rsqrtf(rv[i] + 1e-5f);
      scale[i] = inv;
      off2[i] = (br[i] - rm[i]) * inv + beta[i];
    }
  }

  const int b = blockIdx.z, c0 = blockIdx.y * 64, s0 = blockIdx.x * 64;
  const int r = t >> 2, cc = (t & 3) * 16;
  const float* src = x + ((size_t)b * 512 + c0 + r) * 4096 + s0 + cc;
  #pragma unroll
  for (int j = 0; j < 16; j += 4) {
    float4 v = *(const float4*)(src + j);
    tile[r][cc + j + 0] = f2b(v.x);
    tile[r][cc + j + 1] = f2b(v.y);
    tile[r][cc + j + 2] = f2b(v.z);
    tile[r][cc + j + 3] = f2b(v.w);
  }
  __syncthreads();
  unsigned short* dst = xt + ((size_t)b * 4096 + s0 + r) * 512 + c0 + cc;
  bf16x8 o0, o1;
  #pragma unroll
  for (int j = 0; j < 8; ++j) { o0[j] = tile[cc + j][r]; o1[j] = tile[cc + 8 + j][r]; }
  *(bf16x8*)(dst) = o0;
  *(bf16x8*)(dst + 8) = o1;
}

// ---------------- G1: QKV GEMM, 128x128, BK=64, ring-2, swizzled LDS ----------------
__global__ __launch_bounds__(256) void k_qkv(
    const unsigned short* __restrict__ xt, const unsigned short* __restrict__ wqkv,
    const float* __restrict__ bqkv, unsigned short* __restrict__ qkv)
{
  __shared__ unsigned short lds[2][2][8192];  // 64 KB
  const int b = blockIdx.z, o0 = blockIdx.y * 128, s0 = blockIdx.x * 128;
  const int t = threadIdx.x, w = t >> 6, l = t & 63;
  const int wm = w >> 1, wn = w & 1, lr = l & 15;
  const int lkE = (l >> 4) * 8;
  const int swE = (lr & 7) * 8;
  const int cp = (t & 7) ^ ((t >> 3) & 7);

  const unsigned short* Ag = wqkv + (size_t)(o0 + (t >> 3)) * 512 + cp * 8;
  const unsigned short* Bg = xt + ((size_t)b * 4096 + s0 + (t >> 3)) * 512 + cp * 8;

  const f32x4 z = {0.f, 0.f, 0.f, 0.f};
  f32x4 acc[4][4];
  #pragma unroll
  for (int i = 0; i < 4; ++i)
    #pragma unroll
    for (int j = 0; j < 4; ++j) acc[i][j] = z;

#define STG_Q(st, kt) do { \
    _Pragma("unroll") \
    for (int j = 0; j < 4; ++j) { \
      GL16(Ag + (kt) * 64 + j * 32 * 512, (char*)&lds[st][0][0] + j * 4096 + t * 16); \
      GL16(Bg + (kt) * 64 + j * 32 * 512, (char*)&lds[st][1][0] + j * 4096 + t * 16); \
    } \
  } while (0)

  // loads-upfront compute: all 16 ds_read, then 32 MFMA; reads provably retire
  // before the wave reaches the following barrier (every result feeds an MFMA issue).
#define CMP_Q(st) do { \
    const unsigned short* A  = &lds[st][0][0]; \
    const unsigned short* Bl = &lds[st][1][0]; \
    bf16x8 af[2][4], bfr[2][4]; \
    _Pragma("unroll") \
    for (int kc = 0; kc < 2; ++kc) { \
      const int kidx = (kc * 32 + lkE) ^ swE; \
      _Pragma("unroll") \
      for (int mi = 0; mi < 4; ++mi) af[kc][mi] = *(const bf16x8*)(A + (wm * 64 + mi * 16 + lr) * 64 + kidx); \
      _Pragma("unroll") \
      for (int ni = 0; ni < 4; ++ni) bfr[kc][ni] = *(const bf16x8*)(Bl + (wn * 64 + ni * 16 + lr) * 64 + kidx); \
    } \
    _Pragma("unroll") \
    for (int kc = 0; kc < 2; ++kc) \
      _Pragma("unroll") \
      for (int mi = 0; mi < 4; ++mi) \
        _Pragma("unroll") \
        for (int ni = 0; ni < 4; ++ni) \
          acc[mi][ni] = __builtin_amdgcn_mfma_f32_16x16x32_bf16(af[kc][mi], bfr[kc][ni], acc[mi][ni], 0, 0, 0); \
  } while (0)

  STG_Q(0, 0); STG_Q(1, 1);
  #pragma unroll
  for (int kt = 0; kt < 7; ++kt) {
    WAITVM(8);
    __builtin_amdgcn_s_barrier(); SCHEDBAR;
    CMP_Q(kt & 1);
    __builtin_amdgcn_s_barrier(); SCHEDBAR;
    if (kt + 2 < 8) STG_Q(kt & 1, kt + 2);
  }
  WAITVM(0);
  __builtin_amdgcn_s_barrier(); SCHEDBAR;
  CMP_Q(1);   // kt=7

  #pragma unroll
  for (int mi = 0; mi < 4; ++mi) {
    #pragma unroll
    for (int reg = 0; reg < 4; ++reg) {
      const int o = o0 + wm * 64 + mi * 16 + (l >> 4) * 4 + reg;
      const float bias = bqkv[o];
      const size_t base = (size_t)(o >> 8) * 16777216ull + ((size_t)b * 256 + (o & 255)) * 4096;
      #pragma unroll
      for (int ni = 0; ni < 4; ++ni) {
        const int s = s0 + wn * 64 + ni * 16 + lr;
        qkv[base + s] = f2b(acc[mi][ni][reg] + bias);
      }
    }
  }
#undef STG_Q
#undef CMP_Q
}

// ---------------- G2: per-group attention ----------------
__global__ __launch_bounds__(256) void k_attn(const unsigned short* __restrict__ qkv,
                                              unsigned short* __restrict__ yout)
{
  __shared__ unsigned short Vt[64][80];
  __shared__ unsigned short P[4][16][80];
  const int g = blockIdx.x;
  const unsigned short* qg = qkv + (size_t)g * 4096;
  const unsigned short* kg = qkv + 16777216ull + (size_t)g * 4096;
  const unsigned short* vg = qkv + 33554432ull + (size_t)g * 4096;
  const int t = threadIdx.x, w = t >> 6, l = t & 63;
  const int lr = l & 15, lk = (l >> 4) * 8;

  {
    const int j = t >> 2, c0 = (t & 3) * 16;
    bf16x8 a = *(const bf16x8*)(vg + j * 64 + c0);
    bf16x8 bb = *(const bf16x8*)(vg + j * 64 + c0 + 8);
    #pragma unroll
    for (int jj = 0; jj < 8; ++jj) { Vt[c0 + jj][j] = a[jj]; Vt[c0 + 8 + jj][j] = bb[jj]; }
  }

  const f32x4 z = {0.f, 0.f, 0.f, 0.f};
  bf16x8 qf[2];
  #pragma unroll
  for (int kc = 0; kc < 2; ++kc) qf[kc] = *(const bf16x8*)(qg + (w * 16 + lr) * 64 + kc * 32 + lk);
  f32x4 accS[4] = {z, z, z, z};
  #pragma unroll
  for (int jt = 0; jt < 4; ++jt)
    #pragma unroll
    for (int kc = 0; kc < 2; ++kc) {
      bf16x8 kf = *(const bf16x8*)(kg + (jt * 16 + lr) * 64 + kc * 32 + lk);
      accS[jt] = __builtin_amdgcn_mfma_f32_16x16x32_bf16(qf[kc], kf, accS[jt], 0, 0, 0);
    }

  #pragma unroll
  for (int reg = 0; reg < 4; ++reg) {
    float mx = fmaxf(fmaxf(accS[0][reg], accS[1][reg]), fmaxf(accS[2][reg], accS[3][reg]));
    #pragma unroll
    for (int m = 1; m < 16; m <<= 1) mx = fmaxf(mx, __shfl_xor(mx, m, 64));
    float e0 = __expf(accS[0][reg] - mx), e1 = __expf(accS[1][reg] - mx);
    float e2 = __expf(accS[2][reg] - mx), e3 = __expf(accS[3][reg] - mx);
    float sm = e0 + e1 + e2 + e3;
    #pragma unroll
    for (int m = 1; m < 16; m <<= 1) sm += __shfl_xor(sm, m, 64);
    const float rs = 1.f / sm;
    const int row = (l >> 4) * 4 + reg;
    P[w][row][0 * 16 + lr] = f2b(e0 * rs);
    P[w][row][1 * 16 + lr] = f2b(e1 * rs);
    P[w][row][2 * 16 + lr] = f2b(e2 * rs);
    P[w][row][3 * 16 + lr] = f2b(e3 * rs);
  }
  __syncthreads();

  bf16x8 pf[2];
  #pragma unroll
  for (int kc = 0; kc < 2; ++kc) pf[kc] = *(const bf16x8*)(&P[w][lr][kc * 32 + lk]);
  f32x4 accY[4] = {z, z, z, z};
  #pragma unroll
  for (int nt = 0; nt < 4; ++nt)
    #pragma unroll
    for (int kc = 0; kc < 2; ++kc) {
      bf16x8 vf = *(const bf16x8*)(&Vt[nt * 16 + lr][kc * 32 + lk]);
      accY[nt] = __builtin_amdgcn_mfma_f32_16x16x32_bf16(pf[kc], vf, accY[nt], 0, 0, 0);
    }

  unsigned short* yg = yout + (size_t)g * 4096;
  #pragma unroll
  for (int nt = 0; nt < 4; ++nt)
    #pragma unroll
    for (int reg = 0; reg < 4; ++reg) {
      const int i = w * 16 + (l >> 4) * 4 + reg;
      yg[i * 64 + nt * 16 + lr] = f2b(accY[nt][reg]);
    }
}

// ---------------- G3: recon GEMM + BN + residual; reads y DIRECTLY (transpose in staging) ----------------
// B tile [64 cr][128 s] reg-staged from y into padded LDS [64][136]; B-frags via scalar u16 reads.
__global__ __launch_bounds__(256) void k_recon(
    const unsigned short* __restrict__ y, const unsigned short* __restrict__ wrb,
    const float* __restrict__ scale, const float* __restrict__ off2,
    const float* __restrict__ x, float* __restrict__ out)
{
  __shared__ unsigned short Alds[2][8192];      // 32 KB, swizzled A (as round-3)
  __shared__ unsigned short Blds[2][64][136];   // 34 KB, y-layout, padded
  const int b = blockIdx.z, o0 = blockIdx.y * 128, s0 = blockIdx.x * 128;
  const int t = threadIdx.x, w = t >> 6, l = t & 63;
  const int wm = w >> 1, wn = w & 1, lr = l & 15;
  const int lkE = (l >> 4) * 8;
  const int swE = (lr & 7) * 8;
  const int cp = (t & 7) ^ ((t >> 3) & 7);

  const unsigned short* Ag = wrb + (size_t)(o0 + (t >> 3)) * 256 + cp * 8;
  const unsigned short* Bg = y + ((size_t)b * 256 + (t >> 2)) * 4096 + s0 + (t & 3) * 32;
  const int brow = t >> 2, bcol = (t & 3) * 32;

#define STG_A(st, kt) do { \
    _Pragma("unroll") \
    for (int j = 0; j < 4; ++j) \
      GL16(Ag + (kt) * 64 + j * 32 * 256, (char*)&Alds[st][0] + j * 4096 + t * 16); \
  } while (0)

#define BLOAD(r0, r1, r2, r3, kt) do { \
    r0 = *(const uint4*)(Bg + (size_t)(kt) * 64 * 4096 + 0); \
    r1 = *(const uint4*)(Bg + (size_t)(kt) * 64 * 4096 + 8); \
    r2 = *(const uint4*)(Bg + (size_t)(kt) * 64 * 4096 + 16); \
    r3 = *(const uint4*)(Bg + (size_t)(kt) * 64 * 4096 + 24); \
  } while (0)

#define BWRITE(st, r0, r1, r2, r3) do { \
    *(uint4*)&Blds[st][brow][bcol + 0]  = r0; \
    *(uint4*)&Blds[st][brow][bcol + 8]  = r1; \
    *(uint4*)&Blds[st][brow][bcol + 16] = r2; \
    *(uint4*)&Blds[st][brow][bcol + 24] = r3; \
  } while (0)

  const f32x4 z = {0.f, 0.f, 0.f, 0.f};
  f32x4 acc[4][4];
  #pragma unroll
  for (int i = 0; i < 4; ++i)
    #pragma unroll
    for (int j = 0; j < 4; ++j) acc[i][j] = z;

#define CMP_R(st) do { \
    _Pragma("unroll") \
    for (int kc = 0; kc < 2; ++kc) { \
      const int kidxA = (kc * 32 + lkE) ^ swE; \
      bf16x8 af[4], bfr[4]; \
      _Pragma("unroll") \
      for (int mi = 0; mi < 4; ++mi) af[mi] = *(const bf16x8*)(&Alds[st][0] + (wm * 64 + mi * 16 + lr) * 64 + kidxA); \
      _Pragma("unroll") \
      for (int ni = 0; ni < 4; ++ni) { \
        const int scol = wn * 64 + ni * 16 + lr; \
        _Pragma("unroll") \
        for (int e = 0; e < 8; ++e) bfr[ni][e] = (short)Blds[st][kc * 32 + lkE + e][scol]; \
      } \
      _Pragma("unroll") \
      for (int mi = 0; mi < 4; ++mi) \
        _Pragma("unroll") \
        for (int ni = 0; ni < 4; ++ni) \
          acc[mi][ni] = __builtin_amdgcn_mfma_f32_16x16x32_bf16(af[mi], bfr[ni], acc[mi][ni], 0, 0, 0); \
    } \
  } while (0)

  uint4 a0, a1, a2, a3, b0, b1, b2, b3;
  // prologue (issue order pinned so WAITVM counts are valid)
  STG_A(0, 0);           SCHEDBAR;
  BLOAD(a0, a1, a2, a3, 0); SCHEDBAR;
  STG_A(1, 1);           SCHEDBAR;
  BLOAD(b0, b1, b2, b3, 1); SCHEDBAR;
  WAITVM(8);                           // A0 + B0 done
  BWRITE(0, a0, a1, a2, a3);
  WAITLGKM;
  __builtin_amdgcn_s_barrier(); SCHEDBAR;
  // kt = 0
  CMP_R(0);
  __builtin_amdgcn_s_barrier(); SCHEDBAR;
  STG_A(0, 2); SCHEDBAR;
  BLOAD(a0, a1, a2, a3, 2); SCHEDBAR;
  WAITVM(8);                           // A1 + B1 done
  BWRITE(1, b0, b1, b2, b3);
  WAITLGKM;
  __builtin_amdgcn_s_barrier(); SCHEDBAR;
  // kt = 1
  CMP_R(1);
  __builtin_amdgcn_s_barrier(); SCHEDBAR;
  STG_A(1, 3); SCHEDBAR;
  BLOAD(b0, b1, b2, b3, 3); SCHEDBAR;
  WAITVM(8);                           // A2 + B2 done
  BWRITE(0, a0, a1, a2, a3);
  WAITLGKM;
  __builtin_amdgcn_s_barrier(); SCHEDBAR;
  // kt = 2
  CMP_R(0);
  __builtin_amdgcn_s_barrier(); SCHEDBAR;
  WAITVM(0);                           // A3 + B3 done
  BWRITE(1, b0, b1, b2, b3);
  WAITLGKM;
  __builtin_amdgcn_s_barrier(); SCHEDBAR;
  // kt = 3
  CMP_R(1);

  // epilogue: out = acc*scale[o] + off2[o] + x
  #pragma unroll
  for (int mi = 0; mi < 4; ++mi) {
    #pragma unroll
    for (int reg = 0; reg < 4; ++reg) {
      const int o = o0 + wm * 64 + mi * 16 + (l >> 4) * 4 + reg;
      const float sc = scale[o], of = off2[o];
      const size_t base = ((size_t)b * 512 + o) * 4096;
      #pragma unroll
      for (int ni = 0; ni < 4; ++ni) {
        const int s = s0 + wn * 64 + ni * 16 + lr;
        const size_t idx = base + s;
        out[idx] = acc[mi][ni][reg] * sc + of + x[idx];
      }
    }
  }
#undef STG_A
#undef BLOAD
#undef BWRITE
#undef CMP_R
}

extern "C" void kernel_launch(void* const* d_in, const int* in_sizes, int n_in,
                              void* d_out, int out_size, void* d_ws, size_t ws_size,
                              hipStream_t stream)
{
  const float* x     = (const float*)d_in[0];
  const float* Wq    = (const float*)d_in[1];
  const float* bq    = (const float*)d_in[2];
  const float* Wk    = (const float*)d_in[3];
  const float* bk    = (const float*)d_in[4];
  const float* Wv    = (const float*)d_in[5];
  const float* bv    = (const float*)d_in[6];
  const float* Wr    = (const float*)d_in[7];
  const float* br    = (const float*)d_in[8];
  const float* gamma = (const float*)d_in[9];
  const float* beta  = (const float*)d_in[10];
  const float* rm    = (const float*)d_in[11];
  const float* rv    = (const float*)d_in[12];

  char* ws = (char*)d_ws;
  unsigned short* wqkv  = (unsigned short*)(ws + OFF_WQKV);
  unsigned short* wrb   = (unsigned short*)(ws + OFF_WR);
  float* bqkv  = (float*)(ws + OFF_BQKV);
  float* scale = (float*)(ws + OFF_SCALE);
  float* off2  = (float*)(ws + OFF_OFF2);
  unsigned short* xt  = (unsigned short*)(ws + OFF_XT);
  unsigned short* yb  = (unsigned short*)(ws + OFF_Y);
  unsigned short* qkv = (unsigned short*)(ws + OFF_Q);
  float* out = (float*)d_out;

  hipLaunchKernelGGL(k_xt, dim3(64, 8, 16), dim3(256), 0, stream,
                     x, xt, Wq, bq, Wk, bk, Wv, bv, Wr, br, gamma, beta, rm, rv,
                     wqkv, wrb, bqkv, scale, off2);
  hipLaunchKernelGGL(k_qkv, dim3(32, 6, 16), dim3(256), 0, stream, xt, wqkv, bqkv, qkv);
  hipLaunchKernelGGL(k_attn, dim3(4096), dim3(256), 0, stream, qkv, yb);
  hipLaunchKernelGGL(k_recon, dim3(32, 4, 16), dim3(256), 0, stream, yb, wrb, scale, off2, x, out);
}